// Round 1
// baseline (138.985 us; speedup 1.0000x reference)
//
#include <hip/hip_runtime.h>

// SharedGroupLinearLayer: out = softmax(X·r) -combined dual 64x64 linear.
// N = 2048*8*16 = 262144 tokens, DIN = DOUT = 64, NT = 2.
// out[n,o] = (X·w1^T + b1)[n,o] + att0[n] * (X·(w0-w1)^T + (b0-b1))[n,o]
// att0[n] = sigmoid(l0-l1), l_t = X[n,:]·read_w[:,t]
//
// Memory-bound: 64 MB read + 64 MB write -> ~20 us floor @ 6.3 TB/s.
// MFMA bf16 16x16x32; weights live in registers (loop-invariant B-frags).

#define NTOK   262144
#define GPW    4          // 16-token groups per wave
#define NBLK   1024       // 1024 blk * 4 waves * 4 groups * 16 tok = 262144

typedef short bf16x8 __attribute__((ext_vector_type(8)));
typedef float f32x4  __attribute__((ext_vector_type(4)));

__device__ __forceinline__ short f2bf(float f) {
    // fp32 -> bf16 round-to-nearest-even (bit pattern as short)
    unsigned u = __float_as_uint(f);
    u += 0x7fffu + ((u >> 16) & 1u);
    return (short)(u >> 16);
}

__global__ __launch_bounds__(256) void sgll_kernel(
    const float* __restrict__ x,    // (NTOK, 64)
    const float* __restrict__ emb,  // (16, 64) module_emb, j = token%16
    const float* __restrict__ rw,   // (64, 2) read_w[0]
    const float* __restrict__ ws,   // (2, 64, 64) w_stack[t][o][d]
    const float* __restrict__ bs,   // (2, 64)
    float* __restrict__ out)        // (NTOK, 64)
{
    __shared__ float2 rp[64];       // (r0[k], r1[k]) pairs
    const int tid = threadIdx.x;
    if (tid < 64) rp[tid] = make_float2(rw[2 * tid], rw[2 * tid + 1]);

    const int lane = tid & 63;
    const int wv   = tid >> 6;
    const int col  = lane & 15;     // A-row m within group == C/D col == emb row j
    const int q    = lane >> 4;     // quad

    // ---- B fragments: w1 and (w0 - w1), bf16, loop-invariant registers ----
    // B layout (16x16x32): n = lane&15, k = q*8 + j  (j = elem idx)
    bf16x8 B1[2][4], Bd[2][4];
    #pragma unroll
    for (int kt = 0; kt < 2; ++kt) {
        #pragma unroll
        for (int nt = 0; nt < 4; ++nt) {
            const int o = nt * 16 + col;
            const float* p0 = ws + o * 64 + kt * 32 + q * 8;        // w_stack[0]
            const float* p1 = p0 + 4096;                            // w_stack[1]
            float4 a0 = *(const float4*)p0;
            float4 a1 = *(const float4*)(p0 + 4);
            float4 c0 = *(const float4*)p1;
            float4 c1 = *(const float4*)(p1 + 4);
            bf16x8 f1, fd;
            f1[0] = f2bf(c0.x); f1[1] = f2bf(c0.y); f1[2] = f2bf(c0.z); f1[3] = f2bf(c0.w);
            f1[4] = f2bf(c1.x); f1[5] = f2bf(c1.y); f1[6] = f2bf(c1.z); f1[7] = f2bf(c1.w);
            fd[0] = f2bf(a0.x - c0.x); fd[1] = f2bf(a0.y - c0.y);
            fd[2] = f2bf(a0.z - c0.z); fd[3] = f2bf(a0.w - c0.w);
            fd[4] = f2bf(a1.x - c1.x); fd[5] = f2bf(a1.y - c1.y);
            fd[6] = f2bf(a1.z - c1.z); fd[7] = f2bf(a1.w - c1.w);
            B1[kt][nt] = f1;
            Bd[kt][nt] = fd;
        }
    }

    // ---- module_emb slice: loop-invariant per lane (groups are 16-aligned) ----
    float4 e0, e1, e2, e3;
    {
        const float* ep = emb + col * 64 + q * 8;
        e0 = *(const float4*)ep;        e1 = *(const float4*)(ep + 4);
        e2 = *(const float4*)(ep + 32); e3 = *(const float4*)(ep + 36);
    }

    // ---- bias combo: b1[o], (b0-b1)[o] per ntile ----
    float b1v[4], dbv[4];
    #pragma unroll
    for (int nt = 0; nt < 4; ++nt) {
        const int o = nt * 16 + col;
        float t1 = bs[64 + o];
        b1v[nt] = t1;
        dbv[nt] = bs[o] - t1;
    }

    __syncthreads();  // rp ready

    const int gw = blockIdx.x * 4 + wv;           // global wave id
    const size_t tok0 = (size_t)gw * (GPW * 16);  // first token of this wave

    // prefetch group 0
    float4 cx0, cx1, cx2, cx3;
    {
        const float* xp = x + (tok0 + col) * 64 + q * 8;
        cx0 = *(const float4*)xp;        cx1 = *(const float4*)(xp + 4);
        cx2 = *(const float4*)(xp + 32); cx3 = *(const float4*)(xp + 36);
    }

    #pragma unroll
    for (int i = 0; i < GPW; ++i) {
        // ---- prefetch next group's x ----
        float4 nx0, nx1, nx2, nx3;
        if (i + 1 < GPW) {
            const float* xp = x + (tok0 + (size_t)(i + 1) * 16 + col) * 64 + q * 8;
            nx0 = *(const float4*)xp;        nx1 = *(const float4*)(xp + 4);
            nx2 = *(const float4*)(xp + 32); nx3 = *(const float4*)(xp + 36);
        }

        // ---- x + emb (fp32) ----
        float xv[16];
        xv[0]  = cx0.x + e0.x; xv[1]  = cx0.y + e0.y; xv[2]  = cx0.z + e0.z; xv[3]  = cx0.w + e0.w;
        xv[4]  = cx1.x + e1.x; xv[5]  = cx1.y + e1.y; xv[6]  = cx1.z + e1.z; xv[7]  = cx1.w + e1.w;
        xv[8]  = cx2.x + e2.x; xv[9]  = cx2.y + e2.y; xv[10] = cx2.z + e2.z; xv[11] = cx2.w + e2.w;
        xv[12] = cx3.x + e3.x; xv[13] = cx3.y + e3.y; xv[14] = cx3.z + e3.z; xv[15] = cx3.w + e3.w;

        // ---- routing logits (fp32) + 2-way softmax ----
        float l0 = 0.f, l1 = 0.f;
        #pragma unroll
        for (int j = 0; j < 8; ++j) {
            float2 r = rp[q * 8 + j];           // broadcast within quad: conflict-free
            l0 = fmaf(xv[j], r.x, l0);
            l1 = fmaf(xv[j], r.y, l1);
        }
        #pragma unroll
        for (int j = 0; j < 8; ++j) {
            float2 r = rp[32 + q * 8 + j];
            l0 = fmaf(xv[8 + j], r.x, l0);
            l1 = fmaf(xv[8 + j], r.y, l1);
        }
        l0 += __shfl_xor(l0, 16); l0 += __shfl_xor(l0, 32);
        l1 += __shfl_xor(l1, 16); l1 += __shfl_xor(l1, 32);
        // lane now holds full logits for token m = lane&15
        const float att = 1.0f / (1.0f + __expf(l1 - l0));   // att0 = softmax[...,0]

        // ---- A fragments (bf16): A[m=lane&15][k=q*8+j] ----
        bf16x8 A0, A1;
        #pragma unroll
        for (int j = 0; j < 8; ++j) {
            A0[j] = f2bf(xv[j]);       // k = q*8+j        (ktile 0)
            A1[j] = f2bf(xv[8 + j]);   // k = 32 + q*8+j   (ktile 1)
        }

        // ---- MFMA: y1 = X*w1^T, yd = X*(w0-w1)^T  (16 MFMAs / 16 tokens) ----
        f32x4 aY[4], aD[4];
        #pragma unroll
        for (int nt = 0; nt < 4; ++nt) {
            f32x4 z = {0.f, 0.f, 0.f, 0.f};
            f32x4 y = __builtin_amdgcn_mfma_f32_16x16x32_bf16(A0, B1[0][nt], z, 0, 0, 0);
            y       = __builtin_amdgcn_mfma_f32_16x16x32_bf16(A1, B1[1][nt], y, 0, 0, 0);
            f32x4 d = __builtin_amdgcn_mfma_f32_16x16x32_bf16(A0, Bd[0][nt], z, 0, 0, 0);
            d       = __builtin_amdgcn_mfma_f32_16x16x32_bf16(A1, Bd[1][nt], d, 0, 0, 0);
            aY[nt] = y;
            aD[nt] = d;
        }

        // ---- epilogue: out = y1 + b1 + att*(yd + db); C/D: col=lane&15, row=q*4+reg ----
        const size_t rowtok = tok0 + (size_t)i * 16;
        #pragma unroll
        for (int r = 0; r < 4; ++r) {
            const int row = q * 4 + r;
            const float attr = __shfl(att, row);   // src lane row<16 holds token m=row
            float* op = out + (rowtok + row) * 64 + col;
            #pragma unroll
            for (int nt = 0; nt < 4; ++nt) {
                op[nt * 16] = aY[nt][r] + b1v[nt] + attr * (aD[nt][r] + dbv[nt]);
            }
        }

        if (i + 1 < GPW) { cx0 = nx0; cx1 = nx1; cx2 = nx2; cx3 = nx3; }
    }
}

extern "C" void kernel_launch(void* const* d_in, const int* in_sizes, int n_in,
                              void* d_out, int out_size, void* d_ws, size_t ws_size,
                              hipStream_t stream) {
    const float* x   = (const float*)d_in[0];  // (2048, 8, 1024)
    const float* emb = (const float*)d_in[1];  // (1, 1, 1024)
    const float* rw  = (const float*)d_in[2];  // (1, 64, 2)
    const float* wsk = (const float*)d_in[3];  // (2, 64, 64)
    const float* bs  = (const float*)d_in[4];  // (2, 64)
    float* out = (float*)d_out;                // (2048, 8, 1024) fp32

    sgll_kernel<<<NBLK, 256, 0, stream>>>(x, emb, rw, wsk, bs, out);
}

// Round 2
// 132.017 us; speedup vs baseline: 1.0528x; 1.0528x over previous
//
#include <hip/hip_runtime.h>

// SharedGroupLinearLayer R2: latency-bound fix (R1: 8 waves/CU x 1KB in flight
// = 1.5 TB/s by Little's law; measured 1.45).
// out[n,o] = (X w1^T + b1) + att0 * (X (w0-w1)^T + (b0-b1)),
// att0 = sigmoid(l0-l1). emb folded: C_init = b + E·W^T (block-staged, MFMA).
// Orientation D = W·X^T: lane holds 4 consecutive outputs of one token
// -> dwordx4 stores. Weights/R/init live in LDS lane-indexed frag tables.

#define NBLK 1024   // x 4 waves x 4 tiles x 16 tokens = 262144

typedef short bf16x8 __attribute__((ext_vector_type(8)));
typedef float f32x4  __attribute__((ext_vector_type(4)));

union B8 { bf16x8 v; unsigned u[4]; };

__device__ __forceinline__ unsigned pk2bf(float lo, float hi) {
    // round-half-up to bf16, pack two into one dword (1.5 VALU ops/elem)
    unsigned a = __float_as_uint(lo) + 0x8000u;
    unsigned b = __float_as_uint(hi) + 0x8000u;
    return __builtin_amdgcn_perm(b, a, 0x07060302u);
}

__device__ __forceinline__ void pack8(B8& d, float4 p, float4 q) {
    d.u[0] = pk2bf(p.x, p.y); d.u[1] = pk2bf(p.z, p.w);
    d.u[2] = pk2bf(q.x, q.y); d.u[3] = pk2bf(q.z, q.w);
}

__global__ __launch_bounds__(256, 4) void sgll_kernel(
    const float* __restrict__ x,    // (262144, 64)
    const float* __restrict__ emb,  // (16, 64)  row = token % 16
    const float* __restrict__ rw,   // (64, 2)   read_w[0]
    const float* __restrict__ ws,   // (2, 64, 64) w_stack[t][o][d]
    const float* __restrict__ bs,   // (2, 64)
    float* __restrict__ out)        // (262144, 64)
{
    // lane-indexed fragment tables (contiguous b128 reads, conflict-free)
    __shared__ bf16x8 sW1[8][64];   // [kt*4+ot][lane]  w1 A-frags
    __shared__ bf16x8 sWd[8][64];   // w0-w1 A-frags
    __shared__ f32x4  sI1[4][64];   // [ot][lane]  acc init: b1 + E·w1^T
    __shared__ f32x4  sId[4][64];   // db + E·dw^T
    __shared__ f32x4  sIl[64];      // logit acc init: E·R

    const int tid  = threadIdx.x;
    const int lane = tid & 63;
    const int wv   = tid >> 6;
    const int col  = lane & 15;     // token-within-tile == output o_local
    const int q    = lane >> 4;

    // ---- block setup: stage W frags (each thread handles 2 (kt,ot) combos) ----
    #pragma unroll
    for (int c = wv; c < 8; c += 4) {
        const int kt = c >> 2, ot = c & 3;
        const float* p0 = ws + (ot * 16 + col) * 64 + kt * 32 + q * 8;  // w0
        const float* p1 = p0 + 4096;                                    // w1
        float4 a0 = *(const float4*)p0, a1 = *(const float4*)(p0 + 4);
        float4 c0 = *(const float4*)p1, c1 = *(const float4*)(p1 + 4);
        B8 f1, fd;
        pack8(f1, make_float4(c0.x, c0.y, c0.z, c0.w), c1);
        fd.u[0] = pk2bf(a0.x - c0.x, a0.y - c0.y);
        fd.u[1] = pk2bf(a0.z - c0.z, a0.w - c0.w);
        fd.u[2] = pk2bf(a1.x - c1.x, a1.y - c1.y);
        fd.u[3] = pk2bf(a1.z - c1.z, a1.w - c1.w);
        sW1[c][lane] = f1.v;
        sWd[c][lane] = fd.v;
    }

    // ---- R frags (registers, per wave): A[m=col<2][k=kt*32+q*8+j] = rw[k*2+m] ----
    B8 R0, R1;
    {
        float v[8];
        #pragma unroll
        for (int j = 0; j < 8; ++j)
            v[j] = (col < 2) ? rw[(q * 8 + j) * 2 + col] : 0.f;
        pack8(R0, make_float4(v[0], v[1], v[2], v[3]), make_float4(v[4], v[5], v[6], v[7]));
        #pragma unroll
        for (int j = 0; j < 8; ++j)
            v[j] = (col < 2) ? rw[(32 + q * 8 + j) * 2 + col] : 0.f;
        pack8(R1, make_float4(v[0], v[1], v[2], v[3]), make_float4(v[4], v[5], v[6], v[7]));
    }

    __syncthreads();  // W frags ready

    // ---- wave 0: init tables  C_init = bias + E·W^T (MFMA), logit init = E·R ----
    if (wv == 0) {
        const float* ep = emb + col * 64 + q * 8;
        float4 e0 = *(const float4*)ep,        e1 = *(const float4*)(ep + 4);
        float4 e2 = *(const float4*)(ep + 32), e3 = *(const float4*)(ep + 36);
        B8 E0, E1;
        pack8(E0, e0, e1);
        pack8(E1, e2, e3);
        #pragma unroll
        for (int ot = 0; ot < 4; ++ot) {
            float4 b1 = *(const float4*)(bs + 64 + ot * 16 + q * 4);
            float4 b0 = *(const float4*)(bs + ot * 16 + q * 4);
            f32x4 a1 = {b1.x, b1.y, b1.z, b1.w};
            f32x4 ad = {b0.x - b1.x, b0.y - b1.y, b0.z - b1.z, b0.w - b1.w};
            a1 = __builtin_amdgcn_mfma_f32_16x16x32_bf16(sW1[ot][lane],     E0.v, a1, 0, 0, 0);
            a1 = __builtin_amdgcn_mfma_f32_16x16x32_bf16(sW1[4 + ot][lane], E1.v, a1, 0, 0, 0);
            ad = __builtin_amdgcn_mfma_f32_16x16x32_bf16(sWd[ot][lane],     E0.v, ad, 0, 0, 0);
            ad = __builtin_amdgcn_mfma_f32_16x16x32_bf16(sWd[4 + ot][lane], E1.v, ad, 0, 0, 0);
            sI1[ot][lane] = a1;
            sId[ot][lane] = ad;
        }
        f32x4 zl = {0.f, 0.f, 0.f, 0.f};
        zl = __builtin_amdgcn_mfma_f32_16x16x32_bf16(R0.v, E0.v, zl, 0, 0, 0);
        zl = __builtin_amdgcn_mfma_f32_16x16x32_bf16(R1.v, E1.v, zl, 0, 0, 0);
        sIl[lane] = zl;
    }
    __syncthreads();

    // ---- main: 4 tiles/wave, depth-2 prefetch (3 rotating buffers = 2KB in flight) ----
    const long base = (long)(blockIdx.x * 4 + wv) * 64;   // first token
    float4 A[3][4];

    #define LOAD_TILE(buf, t)  do {                                        \
        const float* p = x + (base + (long)(t) * 16 + col) * 64 + q * 8;   \
        A[buf][0] = *(const float4*)p;        A[buf][1] = *(const float4*)(p + 4);  \
        A[buf][2] = *(const float4*)(p + 32); A[buf][3] = *(const float4*)(p + 36); \
    } while (0)

    LOAD_TILE(0, 0);
    LOAD_TILE(1, 1);

    #pragma unroll
    for (int i = 0; i < 4; ++i) {
        const int b = i % 3;
        if (i + 2 < 4) LOAD_TILE((i + 2) % 3, i + 2);

        // cvt current tile to bf16 B-frags: B[tok=col][k=q*8+j (+32)]
        B8 X0, X1;
        pack8(X0, A[b][0], A[b][1]);
        pack8(X1, A[b][2], A[b][3]);

        // routing logits via MFMA; rows 0,1 (q=0 lanes) hold l0,l1 for token=col
        f32x4 lac = sIl[lane];
        lac = __builtin_amdgcn_mfma_f32_16x16x32_bf16(R0.v, X0.v, lac, 0, 0, 0);
        lac = __builtin_amdgcn_mfma_f32_16x16x32_bf16(R1.v, X1.v, lac, 0, 0, 0);
        float att = 1.0f / (1.0f + __expf(lac[1] - lac[0]));  // valid on q=0 lanes
        att = __shfl(att, col);                               // broadcast per token

        const long rowoff = (base + (long)i * 16 + col) * 64;
        #pragma unroll
        for (int ot = 0; ot < 4; ++ot) {
            f32x4 y = sI1[ot][lane];   // bias+emb already inside
            y = __builtin_amdgcn_mfma_f32_16x16x32_bf16(sW1[ot][lane],     X0.v, y, 0, 0, 0);
            y = __builtin_amdgcn_mfma_f32_16x16x32_bf16(sW1[4 + ot][lane], X1.v, y, 0, 0, 0);
            f32x4 d = sId[ot][lane];
            d = __builtin_amdgcn_mfma_f32_16x16x32_bf16(sWd[ot][lane],     X0.v, d, 0, 0, 0);
            d = __builtin_amdgcn_mfma_f32_16x16x32_bf16(sWd[4 + ot][lane], X1.v, d, 0, 0, 0);
            float4 o;
            o.x = fmaf(att, d[0], y[0]);
            o.y = fmaf(att, d[1], y[1]);
            o.z = fmaf(att, d[2], y[2]);
            o.w = fmaf(att, d[3], y[3]);
            *(float4*)(out + rowoff + ot * 16 + q * 4) = o;   // 16B coalesced
        }
    }
    #undef LOAD_TILE
}

extern "C" void kernel_launch(void* const* d_in, const int* in_sizes, int n_in,
                              void* d_out, int out_size, void* d_ws, size_t ws_size,
                              hipStream_t stream) {
    const float* x   = (const float*)d_in[0];
    const float* emb = (const float*)d_in[1];
    const float* rw  = (const float*)d_in[2];
    const float* wsk = (const float*)d_in[3];
    const float* bs  = (const float*)d_in[4];
    float* out = (float*)d_out;
    sgll_kernel<<<NBLK, 256, 0, stream>>>(x, emb, rw, wsk, bs, out);
}

// Round 3
// 128.571 us; speedup vs baseline: 1.0810x; 1.0268x over previous
//
#include <hip/hip_runtime.h>

// SharedGroupLinearLayer R3.
// R2 post-mortem: VGPR=48 proved the compiler sank the prefetch loads
// (3-buffer rotation needed >=90 regs). Effective in-flight ~1.3KB/wave x
// 7 waves/CU -> 2.4 TB/s by Little's law (measured 2.39). Fix: burst-issue
// ALL 4 tiles per wave (16 KB in flight), pinned with sched_barrier(0);
// accumulator-init (bias + emb folded) computed per-wave in registers
// (no 2nd barrier, no LDS init tables).
//
// out[n,o] = (X w1^T + b1) + att0 * (X (w0-w1)^T + (b0-b1)),
// att0 = sigmoid(l0-l1); emb folded into acc init via C0 = b + E·W^T.

#define NBLK 1024   // x 4 waves x 4 tiles x 16 tokens = 262144

typedef short bf16x8 __attribute__((ext_vector_type(8)));
typedef float f32x4  __attribute__((ext_vector_type(4)));

union B8 { bf16x8 v; unsigned u[4]; };

__device__ __forceinline__ unsigned pk2bf(float lo, float hi) {
    unsigned a = __float_as_uint(lo) + 0x8000u;
    unsigned b = __float_as_uint(hi) + 0x8000u;
    return __builtin_amdgcn_perm(b, a, 0x07060302u);
}

__device__ __forceinline__ void pack8(B8& d, float4 p, float4 q) {
    d.u[0] = pk2bf(p.x, p.y); d.u[1] = pk2bf(p.z, p.w);
    d.u[2] = pk2bf(q.x, q.y); d.u[3] = pk2bf(q.z, q.w);
}

__global__ __launch_bounds__(256, 3) void sgll_kernel(
    const float* __restrict__ x,    // (262144, 64)
    const float* __restrict__ emb,  // (16, 64)  row = token % 16
    const float* __restrict__ rw,   // (64, 2)
    const float* __restrict__ ws,   // (2, 64, 64) w_stack[t][o][d]
    const float* __restrict__ bs,   // (2, 64)
    float* __restrict__ out)        // (262144, 64)
{
    __shared__ bf16x8 sW1[8][64];   // [kt*4+ot][lane]  w1 A-frags
    __shared__ bf16x8 sWd[8][64];   // w0-w1 A-frags

    const int tid  = threadIdx.x;
    const int lane = tid & 63;
    const int wv   = tid >> 6;
    const int col  = lane & 15;
    const int q    = lane >> 4;

    // ---- Phase A: stage W frags (waves split the 8 (kt,ot) combos) ----
    #pragma unroll
    for (int c = wv; c < 8; c += 4) {
        const int kt = c >> 2, ot = c & 3;
        const float* p0 = ws + (ot * 16 + col) * 64 + kt * 32 + q * 8;  // w0
        const float* p1 = p0 + 4096;                                    // w1
        float4 a0 = *(const float4*)p0, a1 = *(const float4*)(p0 + 4);
        float4 c0 = *(const float4*)p1, c1 = *(const float4*)(p1 + 4);
        B8 f1, fd;
        pack8(f1, c0, c1);
        fd.u[0] = pk2bf(a0.x - c0.x, a0.y - c0.y);
        fd.u[1] = pk2bf(a0.z - c0.z, a0.w - c0.w);
        fd.u[2] = pk2bf(a1.x - c1.x, a1.y - c1.y);
        fd.u[3] = pk2bf(a1.z - c1.z, a1.w - c1.w);
        sW1[c][lane] = f1.v;
        sWd[c][lane] = fd.v;
    }

    // ---- R frags (regs): A[m=col<2][k=kt*32+q*8+j] = rw[k*2+m] ----
    B8 R0, R1;
    {
        float v[8];
        #pragma unroll
        for (int j = 0; j < 8; ++j)
            v[j] = (col < 2) ? rw[(q * 8 + j) * 2 + col] : 0.f;
        pack8(R0, make_float4(v[0], v[1], v[2], v[3]), make_float4(v[4], v[5], v[6], v[7]));
        #pragma unroll
        for (int j = 0; j < 8; ++j)
            v[j] = (col < 2) ? rw[(32 + q * 8 + j) * 2 + col] : 0.f;
        pack8(R1, make_float4(v[0], v[1], v[2], v[3]), make_float4(v[4], v[5], v[6], v[7]));
    }

    // ---- E frags + bias combos (regs, per wave) ----
    B8 E0, E1;
    {
        const float* ep = emb + col * 64 + q * 8;
        pack8(E0, *(const float4*)ep, *(const float4*)(ep + 4));
        pack8(E1, *(const float4*)(ep + 32), *(const float4*)(ep + 36));
    }
    f32x4 bI1[4], bId[4];
    #pragma unroll
    for (int ot = 0; ot < 4; ++ot) {
        float4 b1 = *(const float4*)(bs + 64 + ot * 16 + q * 4);
        float4 b0 = *(const float4*)(bs + ot * 16 + q * 4);
        bI1[ot][0] = b1.x; bI1[ot][1] = b1.y; bI1[ot][2] = b1.z; bI1[ot][3] = b1.w;
        bId[ot][0] = b0.x - b1.x; bId[ot][1] = b0.y - b1.y;
        bId[ot][2] = b0.z - b1.z; bId[ot][3] = b0.w - b1.w;
    }

    __syncthreads();  // W frags ready (drains the setup loads, not the x burst)

    // ---- Phase B: burst-issue ALL 4 tiles (16 dwordx4 = 16 KB/wave in flight) ----
    const long base = (long)(blockIdx.x * 4 + wv) * 64;   // first token
    float4 buf[4][4];
    #pragma unroll
    for (int t = 0; t < 4; ++t) {
        const float* p = x + (base + (long)t * 16 + col) * 64 + q * 8;
        buf[t][0] = *(const float4*)p;        buf[t][1] = *(const float4*)(p + 4);
        buf[t][2] = *(const float4*)(p + 32); buf[t][3] = *(const float4*)(p + 36);
    }
    __builtin_amdgcn_sched_barrier(0);   // pin: loads stay issued before compute

    // ---- Phase C: acc init via MFMA (overlaps the x burst latency) ----
    f32x4 I1[4], Id[4], Il;
    #pragma unroll
    for (int ot = 0; ot < 4; ++ot) {
        f32x4 a1 = bI1[ot], ad = bId[ot];
        a1 = __builtin_amdgcn_mfma_f32_16x16x32_bf16(sW1[ot][lane],     E0.v, a1, 0, 0, 0);
        a1 = __builtin_amdgcn_mfma_f32_16x16x32_bf16(sW1[4 + ot][lane], E1.v, a1, 0, 0, 0);
        ad = __builtin_amdgcn_mfma_f32_16x16x32_bf16(sWd[ot][lane],     E0.v, ad, 0, 0, 0);
        ad = __builtin_amdgcn_mfma_f32_16x16x32_bf16(sWd[4 + ot][lane], E1.v, ad, 0, 0, 0);
        I1[ot] = a1;
        Id[ot] = ad;
    }
    {
        f32x4 z = {0.f, 0.f, 0.f, 0.f};
        z = __builtin_amdgcn_mfma_f32_16x16x32_bf16(R0.v, E0.v, z, 0, 0, 0);
        z = __builtin_amdgcn_mfma_f32_16x16x32_bf16(R1.v, E1.v, z, 0, 0, 0);
        Il = z;
    }

    // ---- Phase D: 4 tiles, zero-stall from registers (vmcnt 12/8/4/0) ----
    #pragma unroll
    for (int i = 0; i < 4; ++i) {
        B8 X0, X1;
        pack8(X0, buf[i][0], buf[i][1]);
        pack8(X1, buf[i][2], buf[i][3]);

        f32x4 lac = Il;
        lac = __builtin_amdgcn_mfma_f32_16x16x32_bf16(R0.v, X0.v, lac, 0, 0, 0);
        lac = __builtin_amdgcn_mfma_f32_16x16x32_bf16(R1.v, X1.v, lac, 0, 0, 0);
        float att = 1.0f / (1.0f + __expf(lac[1] - lac[0]));  // valid on q=0 lanes
        att = __shfl(att, col);                               // broadcast per token

        const long rowoff = (base + (long)i * 16 + col) * 64;
        #pragma unroll
        for (int ot = 0; ot < 4; ++ot) {
            f32x4 y = I1[ot];
            y = __builtin_amdgcn_mfma_f32_16x16x32_bf16(sW1[ot][lane],     X0.v, y, 0, 0, 0);
            y = __builtin_amdgcn_mfma_f32_16x16x32_bf16(sW1[4 + ot][lane], X1.v, y, 0, 0, 0);
            f32x4 d = Id[ot];
            d = __builtin_amdgcn_mfma_f32_16x16x32_bf16(sWd[ot][lane],     X0.v, d, 0, 0, 0);
            d = __builtin_amdgcn_mfma_f32_16x16x32_bf16(sWd[4 + ot][lane], X1.v, d, 0, 0, 0);
            float4 o;
            o.x = fmaf(att, d[0], y[0]);
            o.y = fmaf(att, d[1], y[1]);
            o.z = fmaf(att, d[2], y[2]);
            o.w = fmaf(att, d[3], y[3]);
            *(float4*)(out + rowoff + ot * 16 + q * 4) = o;   // 16B coalesced
        }
    }
}

extern "C" void kernel_launch(void* const* d_in, const int* in_sizes, int n_in,
                              void* d_out, int out_size, void* d_ws, size_t ws_size,
                              hipStream_t stream) {
    const float* x   = (const float*)d_in[0];
    const float* emb = (const float*)d_in[1];
    const float* rw  = (const float*)d_in[2];
    const float* wsk = (const float*)d_in[3];
    const float* bs  = (const float*)d_in[4];
    float* out = (float*)d_out;
    sgll_kernel<<<NBLK, 256, 0, stream>>>(x, emb, rw, wsk, bs, out);
}

// Round 4
// 126.702 us; speedup vs baseline: 1.0969x; 1.0148x over previous
//
#include <hip/hip_runtime.h>

// SharedGroupLinearLayer R4.
// R3 post-mortem: burst held in regs (VGPR 80) but BW stuck at 2.46 TB/s.
// Wave lifetime ~13us, loads outstanding only during one short burst ->
// duty cycle ~15% -> avg outstanding/CU ~13KB -> 2.5 TB/s (matches).
// Fix: amortize setup (512 blocks x 8 tiles/wave) + depth-4 rotating
// register pipeline so bytes stay in flight continuously.
//
// out[n,o] = (X w1^T + b1) + att0 * (X (w0-w1)^T + (b0-b1)),
// att0 = sigmoid(l0-l1); emb folded into acc init: C0 = b + E·W^T.

#define NBLK 512    // x 4 waves x 8 tiles x 16 tokens = 262144
#define TPW  8      // tiles per wave
#define DEPTH 4     // register pipeline depth (tiles in flight)

typedef short bf16x8 __attribute__((ext_vector_type(8)));
typedef float f32x4  __attribute__((ext_vector_type(4)));

union B8 { bf16x8 v; unsigned u[4]; };

__device__ __forceinline__ unsigned pk2bf(float lo, float hi) {
    unsigned a = __float_as_uint(lo) + 0x8000u;
    unsigned b = __float_as_uint(hi) + 0x8000u;
    return __builtin_amdgcn_perm(b, a, 0x07060302u);
}

__device__ __forceinline__ void pack8(B8& d, float4 p, float4 q) {
    d.u[0] = pk2bf(p.x, p.y); d.u[1] = pk2bf(p.z, p.w);
    d.u[2] = pk2bf(q.x, q.y); d.u[3] = pk2bf(q.z, q.w);
}

__global__ __launch_bounds__(256, 3) void sgll_kernel(
    const float* __restrict__ x,    // (262144, 64)
    const float* __restrict__ emb,  // (16, 64)  row = token % 16
    const float* __restrict__ rw,   // (64, 2)
    const float* __restrict__ ws,   // (2, 64, 64) w_stack[t][o][d]
    const float* __restrict__ bs,   // (2, 64)
    float* __restrict__ out)        // (262144, 64)
{
    __shared__ bf16x8 sW1[8][64];   // [kt*4+ot][lane]  w1 A-frags
    __shared__ bf16x8 sWd[8][64];   // w0-w1 A-frags

    const int tid  = threadIdx.x;
    const int lane = tid & 63;
    const int wv   = tid >> 6;
    const int col  = lane & 15;
    const int q    = lane >> 4;

    // ---- setup: stage W frags (waves split the 8 (kt,ot) combos) ----
    #pragma unroll
    for (int c = wv; c < 8; c += 4) {
        const int kt = c >> 2, ot = c & 3;
        const float* p0 = ws + (ot * 16 + col) * 64 + kt * 32 + q * 8;  // w0
        const float* p1 = p0 + 4096;                                    // w1
        float4 a0 = *(const float4*)p0, a1 = *(const float4*)(p0 + 4);
        float4 c0 = *(const float4*)p1, c1 = *(const float4*)(p1 + 4);
        B8 f1, fd;
        pack8(f1, c0, c1);
        fd.u[0] = pk2bf(a0.x - c0.x, a0.y - c0.y);
        fd.u[1] = pk2bf(a0.z - c0.z, a0.w - c0.w);
        fd.u[2] = pk2bf(a1.x - c1.x, a1.y - c1.y);
        fd.u[3] = pk2bf(a1.z - c1.z, a1.w - c1.w);
        sW1[c][lane] = f1.v;
        sWd[c][lane] = fd.v;
    }

    // ---- R frags (regs): A[m=col<2][k=kt*32+q*8+j] = rw[k*2+m] ----
    B8 R0, R1;
    {
        float v[8];
        #pragma unroll
        for (int j = 0; j < 8; ++j)
            v[j] = (col < 2) ? rw[(q * 8 + j) * 2 + col] : 0.f;
        pack8(R0, make_float4(v[0], v[1], v[2], v[3]), make_float4(v[4], v[5], v[6], v[7]));
        #pragma unroll
        for (int j = 0; j < 8; ++j)
            v[j] = (col < 2) ? rw[(32 + q * 8 + j) * 2 + col] : 0.f;
        pack8(R1, make_float4(v[0], v[1], v[2], v[3]), make_float4(v[4], v[5], v[6], v[7]));
    }

    // ---- E frags + bias combos (regs, per wave) ----
    B8 E0, E1;
    {
        const float* ep = emb + col * 64 + q * 8;
        pack8(E0, *(const float4*)ep, *(const float4*)(ep + 4));
        pack8(E1, *(const float4*)(ep + 32), *(const float4*)(ep + 36));
    }
    f32x4 bI1[4], bId[4];
    #pragma unroll
    for (int ot = 0; ot < 4; ++ot) {
        float4 b1 = *(const float4*)(bs + 64 + ot * 16 + q * 4);
        float4 b0 = *(const float4*)(bs + ot * 16 + q * 4);
        bI1[ot][0] = b1.x; bI1[ot][1] = b1.y; bI1[ot][2] = b1.z; bI1[ot][3] = b1.w;
        bId[ot][0] = b0.x - b1.x; bId[ot][1] = b0.y - b1.y;
        bId[ot][2] = b0.z - b1.z; bId[ot][3] = b0.w - b1.w;
    }

    __syncthreads();  // W frags ready

    // ---- prologue: fill the pipeline (DEPTH tiles = 16 dwordx4 in flight) ----
    const long base = (long)(blockIdx.x * 4 + wv) * (TPW * 16);   // first token
    float4 buf[DEPTH][4];
    #pragma unroll
    for (int t = 0; t < DEPTH; ++t) {
        const float* p = x + (base + (long)t * 16 + col) * 64 + q * 8;
        buf[t][0] = *(const float4*)p;        buf[t][1] = *(const float4*)(p + 4);
        buf[t][2] = *(const float4*)(p + 32); buf[t][3] = *(const float4*)(p + 36);
    }
    __builtin_amdgcn_sched_barrier(0);   // pin the burst before compute

    // ---- acc init via MFMA (overlaps prologue load latency) ----
    f32x4 I1[4], Id[4], Il;
    #pragma unroll
    for (int ot = 0; ot < 4; ++ot) {
        f32x4 a1 = bI1[ot], ad = bId[ot];
        a1 = __builtin_amdgcn_mfma_f32_16x16x32_bf16(sW1[ot][lane],     E0.v, a1, 0, 0, 0);
        a1 = __builtin_amdgcn_mfma_f32_16x16x32_bf16(sW1[4 + ot][lane], E1.v, a1, 0, 0, 0);
        ad = __builtin_amdgcn_mfma_f32_16x16x32_bf16(sWd[ot][lane],     E0.v, ad, 0, 0, 0);
        ad = __builtin_amdgcn_mfma_f32_16x16x32_bf16(sWd[4 + ot][lane], E1.v, ad, 0, 0, 0);
        I1[ot] = a1;
        Id[ot] = ad;
    }
    {
        f32x4 z = {0.f, 0.f, 0.f, 0.f};
        z = __builtin_amdgcn_mfma_f32_16x16x32_bf16(R0.v, E0.v, z, 0, 0, 0);
        z = __builtin_amdgcn_mfma_f32_16x16x32_bf16(R1.v, E1.v, z, 0, 0, 0);
        Il = z;
    }

    // ---- steady state: consume tile i, refill slot with tile i+DEPTH ----
    #pragma unroll
    for (int i = 0; i < TPW; ++i) {
        const int b = i & (DEPTH - 1);

        B8 X0, X1;
        pack8(X0, buf[b][0], buf[b][1]);
        pack8(X1, buf[b][2], buf[b][3]);

        // refill the slot immediately after the consume reads (keeps queue full)
        if (i + DEPTH < TPW) {
            const float* p = x + (base + (long)(i + DEPTH) * 16 + col) * 64 + q * 8;
            buf[b][0] = *(const float4*)p;        buf[b][1] = *(const float4*)(p + 4);
            buf[b][2] = *(const float4*)(p + 32); buf[b][3] = *(const float4*)(p + 36);
        }

        f32x4 lac = Il;
        lac = __builtin_amdgcn_mfma_f32_16x16x32_bf16(R0.v, X0.v, lac, 0, 0, 0);
        lac = __builtin_amdgcn_mfma_f32_16x16x32_bf16(R1.v, X1.v, lac, 0, 0, 0);
        float att = 1.0f / (1.0f + __expf(lac[1] - lac[0]));  // valid on q=0 lanes
        att = __shfl(att, col);                               // broadcast per token

        const long rowoff = (base + (long)i * 16 + col) * 64;
        #pragma unroll
        for (int ot = 0; ot < 4; ++ot) {
            f32x4 y = I1[ot];
            y = __builtin_amdgcn_mfma_f32_16x16x32_bf16(sW1[ot][lane],     X0.v, y, 0, 0, 0);
            y = __builtin_amdgcn_mfma_f32_16x16x32_bf16(sW1[4 + ot][lane], X1.v, y, 0, 0, 0);
            f32x4 d = Id[ot];
            d = __builtin_amdgcn_mfma_f32_16x16x32_bf16(sWd[ot][lane],     X0.v, d, 0, 0, 0);
            d = __builtin_amdgcn_mfma_f32_16x16x32_bf16(sWd[4 + ot][lane], X1.v, d, 0, 0, 0);
            float4 o;
            o.x = fmaf(att, d[0], y[0]);
            o.y = fmaf(att, d[1], y[1]);
            o.z = fmaf(att, d[2], y[2]);
            o.w = fmaf(att, d[3], y[3]);
            *(float4*)(out + rowoff + ot * 16 + q * 4) = o;   // 16B coalesced
        }
    }
}

extern "C" void kernel_launch(void* const* d_in, const int* in_sizes, int n_in,
                              void* d_out, int out_size, void* d_ws, size_t ws_size,
                              hipStream_t stream) {
    const float* x   = (const float*)d_in[0];
    const float* emb = (const float*)d_in[1];
    const float* rw  = (const float*)d_in[2];
    const float* wsk = (const float*)d_in[3];
    const float* bs  = (const float*)d_in[4];
    float* out = (float*)d_out;
    sgll_kernel<<<NBLK, 256, 0, stream>>>(x, emb, rw, wsk, bs, out);
}